// Round 8
// baseline (172.850 us; speedup 1.0000x reference)
//
#include <hip/hip_runtime.h>

#define TINYF 1e-8f
#define NITER 50

typedef __attribute__((ext_vector_type(2))) float v2f;

// Wave-wide DPP shifts (verified gfx950, R5-R7): 0x138 = wave_shr1 (lane i <- i-1,
// 0 into lane 0), 0x130 = wave_shl1 (lane i <- i+1, 0 into lane 63).
__device__ __forceinline__ float wWs(float v) {
    return __int_as_float(__builtin_amdgcn_update_dpp(0, __float_as_int(v), 0x138, 0xf, 0xf, true));
}
__device__ __forceinline__ float wEs(float v) {
    return __int_as_float(__builtin_amdgcn_update_dpp(0, __float_as_int(v), 0x130, 0xf, 0xf, true));
}
__device__ __forceinline__ v2f wW(v2f v) { v2f r; r.x = wWs(v.x); r.y = wWs(v.y); return r; }
__device__ __forceinline__ v2f wE(v2f v) { v2f r; r.x = wEs(v.x); r.y = wEs(v.y); return r; }
__device__ __forceinline__ v2f rcp2(v2f v) {
    v2f r; r.x = __builtin_amdgcn_rcpf(v.x); r.y = __builtin_amdgcn_rcpf(v.y); return r;
}
__device__ __forceinline__ v2f pfma(float k, v2f a, v2f c) {
    v2f kv; kv.x = k; kv.y = k;
    return __builtin_elementwise_fma(kv, a, c);
}

// R8: 8 waves = one 48x48 crop, 3-row packed bands. Lane l (0..47) owns
// column l (lanes 48-63 idle/zero). Wave W holds rows [3W,3W+3) in .x and
// [24+3W,24+3W+3) in .y. Same verified tap set / parity exchange / seam
// scheme as R6/R7, but 2x the waves (5120 = 5 waves/SIMD) at ~equal
// per-crop issue: R7 showed the stall is TLP starvation (1.45 waves/SIMD),
// R5 showed 5 waves/SIMD sustains ~69% busy.
__global__ void __launch_bounds__(512)
sinkhorn_8w3(const float* __restrict__ hm_gt,
             const float* __restrict__ hm_pred,
             const int* __restrict__ tops,
             float* __restrict__ out) {
    // ES[parity][slot 0..9][4][64]; slot = W+1. Slot rows {0,1} = band rows
    // {0,1} (read as +3,+4 by wave below); rows {2,3} = band rows {1,2}
    // (read as -2,-1 by wave above). Guards: slot0 rows2,3 .x = 0 (crop top);
    // slot9 rows0,1 .y = 0 (crop bottom). Seam: W7 .x rows 1,2 (crop 22,23)
    // -> slot0 rows2,3 .y ; W0 .y rows 0,1 (crop 24,25) -> slot9 rows0,1 .x.
    __shared__ v2f ES[2][10][4][64];
    __shared__ float sred[2][8];

    const int t = threadIdx.x;
    const int W = t >> 6;                  // wave 0..7
    const int l = t & 63;                  // column (0..47 active)
    const bool act = (l < 48);

    // zero guards (both parities)
    if (W < 4) {
        const int p = W >> 1, r = W & 1;
        ((float*)&ES[p][0][2 + r][l])[0] = 0.f;
    } else {
        const int p = (W - 4) >> 1, r = W & 1;
        ((float*)&ES[p][9][r][l])[1] = 0.f;
    }

    const int blk = blockIdx.x;            // ((bi*8+rr)*5+cc)
    const int bi = blk / 40, rr = (blk / 5) % 8, cc = blk % 5;
    const int y0 = tops[(bi * 8 + rr) * 2 + 0];
    const int x0 = tops[(bi * 8 + rr) * 2 + 1];
    const float* srcA = hm_gt + (size_t)(bi * 5 + cc) * 25600;
    const float* srcB = hm_pred + (size_t)(bi * 5 + cc) * 25600;

    // ---- load own two 3-row column segments of both crops; block-reduce sums ----
    v2f va[3], vb[3];
    float sA = 0.f, sB = 0.f;
    const int rbx = y0 + 3 * W;            // .x band
    const int rby = y0 + 24 + 3 * W;       // .y band
#pragma unroll
    for (int r = 0; r < 3; ++r) {
        const int gx = (rbx + r) * 160 + x0 + l;
        const int gy = (rby + r) * 160 + x0 + l;
        va[r].x = act ? srcA[gx] : 0.f;
        va[r].y = act ? srcA[gy] : 0.f;
        vb[r].x = act ? srcB[gx] : 0.f;
        vb[r].y = act ? srcB[gy] : 0.f;
        sA += va[r].x + va[r].y;
        sB += vb[r].x + vb[r].y;
    }
#pragma unroll
    for (int o = 1; o < 64; o <<= 1) {
        sA += __shfl_xor(sA, o, 64);
        sB += __shfl_xor(sB, o, 64);
    }
    if (l == 0) { sred[0][W] = sA; sred[1][W] = sB; }
    __syncthreads();                       // also makes guard zeros visible
    sA = 0.f; sB = 0.f;
#pragma unroll
    for (int w = 0; w < 8; ++w) { sA += sred[0][w]; sB += sred[1][w]; }
    const float nA = 1.0f / (sA + TINYF);
    const float nB = 1.0f / (sB + TINYF);
#pragma unroll
    for (int r = 0; r < 3; ++r) {
        va[r].x *= nA; va[r].y *= nA;
        vb[r].x *= nB; vb[r].y *= nB;
    }

    // Gibbs weights (same expressions as the verified rounds -> same values)
    const float e10 = expf(-1.0f / 0.1f);
    const float e2  = expf(-sqrtf(2.0f) / 0.1f);
    const float e20 = expf(-2.0f / 0.1f);
    const v2f tiny = {TINYF, TINYF};

    v2f xu[3], xv[3];
    const float u0 = 1.0f / 2304.0f;
#pragma unroll
    for (int r = 0; r < 3; ++r) { xu[r].x = act ? u0 : 0.f; xu[r].y = act ? u0 : 0.f; }

    // horizontal prep arrays of the CURRENT field (live across the barrier)
    v2f s1o[3], s2o[3];
    auto prep = [&](const v2f (&x)[3]) {
#pragma unroll
        for (int r = 0; r < 3; ++r) {
            const v2f w1 = wW(x[r]), e1 = wE(x[r]);
            s1o[r] = w1 + e1;
            s2o[r] = wW(w1) + wE(e1);
        }
    };

    auto publish = [&](const v2f (&y)[3], int q) {
        ES[q][W + 1][0][l] = y[0];
        ES[q][W + 1][1][l] = y[1];
        ES[q][W + 1][2][l] = y[1];
        ES[q][W + 1][3][l] = y[2];
        if (W == 7) {   // seam: crop rows 22,23 feed .y up-halo of wave 0
            ((float*)&ES[q][0][2][l])[1] = y[1].x;
            ((float*)&ES[q][0][3][l])[1] = y[2].x;
        }
        if (W == 0) {   // seam: crop rows 24,25 feed .x down-halo of wave 7
            ((float*)&ES[q][9][0][l])[0] = y[0].y;
            ((float*)&ES[q][9][1][l])[0] = y[1].y;
        }
    };

    // One half-iteration (caller issues __syncthreads() after):
    // reads halos from parity p, combine+rcp fused, publish to parity q,
    // then prep(o) pre-barrier (hides write drain + barrier skew).
    auto half = [&](const v2f (&x)[3], v2f (&o)[3], const v2f (&co)[3],
                    int p, int q) {
        const v2f um2 = ES[p][W][2][l];        // band row -2
        const v2f um1 = ES[p][W][3][l];        // band row -1
        const v2f hp3 = ES[p][W + 2][0][l];    // band row +3
        const v2f hp4 = ES[p][W + 2][1][l];    // band row +4
        v2f a;
        // r=1 (halo only in the e20 term -> latency-tolerant)
        a = x[1];
        a = pfma(e10, s1o[1] + (x[0] + x[2]), a);
        a = pfma(e2,  s1o[0] + s1o[2], a);
        a = pfma(e20, s2o[1] + (um1 + hp3), a);
        o[1] = co[1] * rcp2(a + tiny);
        ES[q][W + 1][1][l] = o[1];
        ES[q][W + 1][2][l] = o[1];
        // halo horizontal sums for rows 0,2 diagonals
        const v2f s1m = wW(um1) + wE(um1);
        const v2f s1p = wW(hp3) + wE(hp3);
        // r=0
        a = x[0];
        a = pfma(e10, s1o[0] + (um1 + x[1]), a);
        a = pfma(e2,  s1m + s1o[1], a);
        a = pfma(e20, s2o[0] + (um2 + x[2]), a);
        o[0] = co[0] * rcp2(a + tiny);
        ES[q][W + 1][0][l] = o[0];
        // r=2
        a = x[2];
        a = pfma(e10, s1o[2] + (x[1] + hp3), a);
        a = pfma(e2,  s1o[1] + s1p, a);
        a = pfma(e20, s2o[2] + (x[0] + hp4), a);
        o[2] = co[2] * rcp2(a + tiny);
        ES[q][W + 1][3][l] = o[2];
        // seams
        if (W == 7) {
            ((float*)&ES[q][0][2][l])[1] = o[1].x;
            ((float*)&ES[q][0][3][l])[1] = o[2].x;
        }
        if (W == 0) {
            ((float*)&ES[q][9][0][l])[0] = o[0].y;
            ((float*)&ES[q][9][1][l])[0] = o[1].y;
        }
        // prep of the new field BEFORE the barrier (pure VALU)
        prep(o);
    };

    // seed parity 0 with u0 boundary rows; prep(xu); sync
    publish(xu, 0);
    prep(xu);
    __syncthreads();

    // ---- Sinkhorn iterations: 1 barrier per half-iteration ----
#pragma unroll 1
    for (int it = 0; it < NITER; ++it) {
        half(xu, xv, vb, 0, 1);
        __syncthreads();
        half(xv, xu, va, 1, 0);
        __syncthreads();
    }

    // ---- loss: (u @ M) . v, M = K .* dist (center 0; e5/e8 taps dropped) ----
    const float s2f = sqrtf(2.0f);
    const float m01 = e10, m02 = e20 * 2.0f, m11 = e2 * s2f;
    v2f ls = {0.f, 0.f};
    {
        const v2f um2 = ES[0][W][2][l];
        const v2f um1 = ES[0][W][3][l];
        const v2f hp3 = ES[0][W + 2][0][l];
        const v2f hp4 = ES[0][W + 2][1][l];
        const v2f s1m = wW(um1) + wE(um1);
        const v2f s1p = wW(hp3) + wE(hp3);
        const v2f zero = {0.f, 0.f};
        v2f a;
        // r=0
        a = pfma(m01, s1o[0] + (um1 + xu[1]), zero);
        a = pfma(m11, s1m + s1o[1], a);
        a = pfma(m02, s2o[0] + (um2 + xu[2]), a);
        ls += a * xv[0];
        // r=1
        a = pfma(m01, s1o[1] + (xu[0] + xu[2]), zero);
        a = pfma(m11, s1o[0] + s1o[2], a);
        a = pfma(m02, s2o[1] + (um1 + hp3), a);
        ls += a * xv[1];
        // r=2
        a = pfma(m01, s1o[2] + (xu[1] + hp3), zero);
        a = pfma(m11, s1o[1] + s1p, a);
        a = pfma(m02, s2o[2] + (xu[0] + hp4), a);
        ls += a * xv[2];
    }
    float lsum = ls.x + ls.y;

#pragma unroll
    for (int o = 1; o < 64; o <<= 1) lsum += __shfl_xor(lsum, o, 64);
    if (l == 0) sred[0][W] = lsum;
    __syncthreads();
    if (t == 0) {
        float s = 0.f;
#pragma unroll
        for (int w = 0; w < 8; ++w) s += sred[0][w];
        atomicAdd(out, s);
    }
}

extern "C" void kernel_launch(void* const* d_in, const int* in_sizes, int n_in,
                              void* d_out, int out_size, void* d_ws, size_t ws_size,
                              hipStream_t stream) {
    (void)in_sizes; (void)n_in; (void)out_size; (void)d_ws; (void)ws_size;
    const float* hm_gt = (const float*)d_in[0];
    const float* hm_pred = (const float*)d_in[1];
    const int* tops = (const int*)d_in[2];
    float* out = (float*)d_out;

    hipMemsetAsync(out, 0, sizeof(float), stream);
    sinkhorn_8w3<<<dim3(640), dim3(512), 0, stream>>>(hm_gt, hm_pred, tops, out);
}